// Round 5
// baseline (10553.378 us; speedup 1.0000x reference)
//
#include <hip/hip_runtime.h>

// Shapes: VOCAB=128, EMBED=512, HIDDEN=1024, B=64, T=512. Inputs fp32, x int32.
// ws layout (bytes):
//   tableV : [128 vocab][4096 C] fp16   @ 0         (1 MB)  xin0+bias
//   fcwT   : [1024 k][128 v] fp16       @ 1048576   (256 KB)
//   bar    : [512 words] u32            @ 1310720   (2 KB)  group counters
//   hseq   : [514 buf][64 b][2048 k]f16 @ 1376256   (128.5 MB) fresh h per step
//
// FRESH-BUFFER h EXCHANGE (R1, kept): step it reads buffer it, writes buffer
// it+1. Consumer XCD never touched buffer it+1 before its poll passes, so L2
// cannot hold a stale line -> h loads are PLAIN CACHED dwordx4. Stores are
// agent-scope relaxed atomics (write-through at the L3 coherence point) +
// per-wave s_waitcnt vmcnt(0) BEFORE the arrival add. Line-ownership:
// cg = (blk&7)*16+t ==> every 128-B h line is written only by ONE XCD.
// buffer[t+2][b][1024+u] IS h2[t] -> FC reads hseq directly.
//
// GROUP-GRANULAR DATAFLOW SYNC (this round): the global per-step barrier
// (max over 128 blocks, 512 times) is replaced by 16 monotonic counters:
//   cntL0[m][g] @ word (m*8+g)*16,  cntL1[m][g] @ word (m*8+4+g)*16, g=0..3
// Producers: owner wave (0-3 -> L0, 4-7 -> L1) drains its h stores
// (vmcnt(0)) then lane0 atomicAdd's its block's group g = cg>>5. 128 adds
// per group per step (4 waves x 32 blocks). Consumers: wave w polls ONLY
// its group counter at loop top: w<8 poll cntL0[w&3] >= 128*it (h1 part of
// buffer it, written step it-1); w>=8 poll cntL1[w&3] >= 128*(it-1) (h2
// part, layer1 adds start at it=1). Buffers 0/1 pre-zeroed cover base
// cases. Waves needing slow producers wait while sibling waves load+MFMA
// -> skew overlaps compute instead of stacking through a global max.
// zs is DOUBLE-BUFFERED (96 KB LDS) -> single __syncthreads per step
// (owner reads parity p after sync(it); same-parity writes at it+2 are
// barrier-ordered after that read).
//
// SWIZZLED LDS REDUCTION (R4, kept): zs[p][w][r][rq][col32],
// col32 = (cb*16 + colp) ^ ((rq&1)<<4), colp = j*4+g; 2-way max on writes,
// aligned b128 owner reads (bank conflicts 2.0e8 -> 2.5e7 measured).
// Transcendentals: __expf + division only (proven on this harness).
//
// Block (256 = 2 m x 128 cg): M-half m (rows m*32..+32), col-group cg
// (units cg*8..+8 of BOTH layers). Wave w (12/block): layer = w<4 ? 0 : 1,
// K-chunk kc = w<4 ? w : w-4 (256 halfs); B in REGISTERS; A loaded once,
// used twice (cb=0,1). C-tiles -> LDS -> owner reduction (waves 0-3 layer0
// cells, 4-7 layer1 cells).

typedef _Float16 v8h __attribute__((ext_vector_type(8)));
typedef float v4f __attribute__((ext_vector_type(4)));
typedef _Float16 h2v __attribute__((ext_vector_type(2)));
typedef unsigned long long u64t;

__device__ __forceinline__ float sigf(float x) {
  return 1.0f / (1.0f + __expf(-x));
}
__device__ __forceinline__ float tanhfast(float x) {
  // tanh = 1 - 2/(e^{2x}+1); graceful at +-inf (__expf -> inf/0)
  return 1.0f - 2.0f / (1.0f + __expf(2.0f * x));
}

// ---------------------------------------------------------------- prep ----
__global__ __launch_bounds__(256) void prep_kernel(
    const float* __restrict__ emb, const float* __restrict__ w_ih0,
    const float* __restrict__ b_ih0, const float* __restrict__ b_hh0,
    const float* __restrict__ fc_w, _Float16* __restrict__ tableV,
    _Float16* __restrict__ fcwT, unsigned* __restrict__ zbuf,
    unsigned* __restrict__ bar) {
  const int blk = blockIdx.x, tid = threadIdx.x;
  if (blk < 2048) {
    // tableV[v][C] = emb[v]·w_ih0[row(C)] + b_ih0[row] + b_hh0[row]
    const int C = blk * 2 + (tid >> 7);
    const int v = tid & 127;
    const int row =
        ((C >> 2) & 3) * 1024 + (C >> 5) * 8 + ((C >> 4) & 1) * 4 + (C & 3);
    float acc = b_ih0[row] + b_hh0[row];
    const float* er = emb + v * 512;
    const float* wr = w_ih0 + row * 512;
#pragma unroll 4
    for (int k = 0; k < 512; ++k) acc = fmaf(er[k], wr[k], acc);
    tableV[v * 4096 + C] = (_Float16)acc;
  } else if (blk < 2560) {
    const int idx = (blk - 2048) * 256 + tid;   // [0, 131072)
    const int v = idx & 127, k = idx >> 7;
    fcwT[k * 128 + v] = (_Float16)fc_w[v * 1024 + k];
  } else if (blk < 2592) {
    // zero hseq buffers 0 and 1 (step-0/1 initial h state): 131072 dwords
    const int idx = (blk - 2560) * 256 + tid;
#pragma unroll
    for (int q = 0; q < 16; ++q) zbuf[idx * 16 + q] = 0u;
  } else {
    for (int i = tid; i < 512; i += 256) bar[i] = 0u;
  }
}

// ------------------------------------------------------------ recurrent ----
__global__ __launch_bounds__(768, 1) void lstm_mfma(
    const int* __restrict__ x, const _Float16* __restrict__ tableV,
    const float* __restrict__ w_hh0, const float* __restrict__ w_ih1,
    const float* __restrict__ w_hh1, const float* __restrict__ b_ih1,
    const float* __restrict__ b_hh1, _Float16* __restrict__ hseq,
    unsigned* __restrict__ bar) {
  // double-buffered: [parity][wave12][r4][rq8][col32] floats = 96 KB
  __shared__ __align__(16) float zs[2 * 12 * 4 * 8 * 32];
  const int ZSZ = 12 * 4 * 8 * 32;

  const int tid = threadIdx.x, blk = blockIdx.x;
  const int w = tid >> 6, l = tid & 63;
  const int lane16 = l & 15, quad = l >> 4;
  // XCD-local cg grouping: all 8 writer-blocks of any 128-B h line share
  // blk&7 (== XCD under the %8 round-robin dispatch).
  const int xcd = blk & 7, bidx = blk >> 3;
  const int m = bidx >> 4, cg = xcd * 16 + (bidx & 15);
  const int kc = (w < 4) ? w : (w - 4);

  // --- stage B-fragments into REGISTERS (once) ---
  v8h breg0[8], breg1[8];
  {
    const int g = lane16 >> 2, j = lane16 & 3;
    const float* Wsrc;
    int kbase;
    if (w < 4) {
      Wsrc = w_hh0;
      kbase = kc * 256;
    } else {
      const int kcomb = kc * 256;
      if (kcomb < 1024) {
        Wsrc = w_ih1;
        kbase = kcomb;
      } else {
        Wsrc = w_hh1;
        kbase = kcomb - 1024;
      }
    }
#pragma unroll
    for (int cb = 0; cb < 2; ++cb) {
      const int row = g * 1024 + cg * 8 + cb * 4 + j;
      const float* rp = Wsrc + row * 1024 + kbase + quad * 8;
#pragma unroll
      for (int kk = 0; kk < 8; ++kk) {
        const float4 f0 = *(const float4*)(rp + kk * 32);
        const float4 f1 = *(const float4*)(rp + kk * 32 + 4);
        v8h b;
        b[0] = (_Float16)f0.x; b[1] = (_Float16)f0.y;
        b[2] = (_Float16)f0.z; b[3] = (_Float16)f0.w;
        b[4] = (_Float16)f1.x; b[5] = (_Float16)f1.y;
        b[6] = (_Float16)f1.z; b[7] = (_Float16)f1.w;
        if (cb == 0) breg0[kk] = b; else breg1[kk] = b;
      }
    }
  }

  // --- elementwise-owner constants ---
  const int oj = l & 7, ojj = l & 3, ocb = (l >> 2) & 1;
  const int ob = (w & 3) * 8 + (l >> 3);
  const int obg = m * 32 + ob;
  // swizzle constants
  const int colp = (lane16 & 3) * 4 + (lane16 >> 2);      // j*4+g
  const int cswz = colp ^ ((quad & 1) << 4);              // write col, cb=0
  const int rr = ob & 3, rqo = ob >> 2;                   // owner row split
  const int rcol = (ocb * 16 + ojj * 4) ^ ((rqo & 1) << 4);  // owner read col

  v4f bias4 = {0.f, 0.f, 0.f, 0.f};
  if (w >= 4 && w < 8) {
#pragma unroll
    for (int g = 0; g < 4; ++g) {
      const int row = g * 1024 + cg * 8 + ocb * 4 + ojj;
      bias4[g] = b_ih1[row] + b_hh1[row];
    }
  }
  _Float16 tvh[4] = {0, 0, 0, 0};
  if (w < 4) {
    const int xv = x[obg * 512];
#pragma unroll
    for (int g = 0; g < 4; ++g)
      tvh[g] = tableV[xv * 4096 + cg * 32 + ocb * 16 + g * 4 + ojj];
  }

  float cst = 0.0f;
  // this wave's consumer counter + arrival counter
  const unsigned* poll_cp =
      &bar[(m * 8 + ((w < 8) ? 0 : 4) + (w & 3)) * 16];
  unsigned* arr_cp = &bar[(m * 8 + ((w < 4) ? 0 : 4) + (cg >> 5)) * 16];

  for (int it = 0; it <= 512; ++it) {
    const _Float16* hr = hseq + (size_t)it * 131072;       // fresh buffers
    _Float16* hw = hseq + (size_t)(it + 1) * 131072;
    float* zsp = zs + (it & 1) * ZSZ;

    v4f a00 = {0, 0, 0, 0}, a01 = {0, 0, 0, 0};
    v4f a10 = {0, 0, 0, 0}, a11 = {0, 0, 0, 0};
    const bool active = (w < 4) ? (it < 512) : (it >= 1);
    if (active) {
      // ---- group-granular wait: only my 32 producers, overlapped with
      // sibling waves' loads/MFMA ----
      const unsigned tgt = 128u * (unsigned)((w < 8) ? it : (it - 1));
      while (__hip_atomic_load(poll_cp, __ATOMIC_RELAXED,
                               __HIP_MEMORY_SCOPE_AGENT) < tgt)
        __builtin_amdgcn_s_sleep(1);
      asm volatile("" ::: "memory");

      // A: rows m*32 + mt*16 + lane16, halfs kc*256 + kk*32 + quad*8
      // PLAIN CACHED loads: poll-pass => stores ack'd at L3; fresh addrs
      // => no stale L2 lines on any XCD.
      const _Float16* a0p = hr + (m * 32 + lane16) * 2048 + kc * 256 + quad * 8;
      const _Float16* a1p = a0p + 16 * 2048;
      v8h A0[8], A1[8];
#pragma unroll
      for (int kk = 0; kk < 8; ++kk) A0[kk] = *(const v8h*)(a0p + kk * 32);
#pragma unroll
      for (int kk = 0; kk < 8; ++kk) A1[kk] = *(const v8h*)(a1p + kk * 32);
#pragma unroll
      for (int kk = 0; kk < 8; ++kk) {
        a00 = __builtin_amdgcn_mfma_f32_16x16x32_f16(A0[kk], breg0[kk], a00, 0, 0, 0);
        a10 = __builtin_amdgcn_mfma_f32_16x16x32_f16(A0[kk], breg1[kk], a10, 0, 0, 0);
      }
#pragma unroll
      for (int kk = 0; kk < 8; ++kk) {
        a01 = __builtin_amdgcn_mfma_f32_16x16x32_f16(A1[kk], breg0[kk], a01, 0, 0, 0);
        a11 = __builtin_amdgcn_mfma_f32_16x16x32_f16(A1[kk], breg1[kk], a11, 0, 0, 0);
      }
    }

    // C-tiles -> LDS, swizzled (R4 layout), parity buffer
#pragma unroll
    for (int r = 0; r < 4; ++r) {
      float* zp = &zsp[((w * 4 + r) * 8 + quad) * 32];
      zp[cswz] = a00[r];
      zp[128 + cswz] = a01[r];
      zp[cswz ^ 16] = a10[r];
      zp[128 + (cswz ^ 16)] = a11[r];
    }
    __syncthreads();   // single per-step rendezvous (zs double-buffered)

    // owner reduction + cell update (vector b128 reads, gates contiguous)
    const bool do0 = (w < 4) && (it < 512);
    const bool do1 = (w >= 4 && w < 8) && (it >= 1);
    if (do0 || do1) {
      v4f z;
      if (do0) {
        z[0] = (float)tvh[0]; z[1] = (float)tvh[1];
        z[2] = (float)tvh[2]; z[3] = (float)tvh[3];
#pragma unroll
        for (int wv = 0; wv < 4; ++wv)
          z += *(const v4f*)&zsp[((wv * 4 + rr) * 8 + rqo) * 32 + rcol];
      } else {
        z = bias4;
#pragma unroll
        for (int wv = 4; wv < 12; ++wv)
          z += *(const v4f*)&zsp[((wv * 4 + rr) * 8 + rqo) * 32 + rcol];
      }
      const float ig = sigf(z[0]), fg = sigf(z[1]);
      const float gg = tanhfast(z[2]), og = sigf(z[3]);
      cst = fg * cst + ig * gg;
      const float hv = og * tanhfast(cst);

      // pack 8 unit-lanes (same b) -> two 8-B stores (lanes oj==0, oj==4)
      const unsigned hu =
          (unsigned)__builtin_bit_cast(unsigned short, (_Float16)hv);
      const unsigned p1 = (unsigned)__shfl_xor((int)hu, 1, 64);
      const unsigned lo = (oj & 1) ? ((p1 & 0xffffu) | (hu << 16))
                                   : ((hu & 0xffffu) | (p1 << 16));
      const unsigned p2 = (unsigned)__shfl_xor((int)lo, 2, 64);
      if ((oj & 3) == 0) {
        const u64t val = (u64t)lo | ((u64t)p2 << 32);
        if (do0) {
          __hip_atomic_store((u64t*)(hw + obg * 2048 + cg * 8 + oj), val,
                             __ATOMIC_RELAXED, __HIP_MEMORY_SCOPE_AGENT);
        } else {
          __hip_atomic_store((u64t*)(hw + obg * 2048 + 1024 + cg * 8 + oj),
                             val, __ATOMIC_RELAXED, __HIP_MEMORY_SCOPE_AGENT);
        }
      }
      // ---- per-wave arrival: drain MY stores to L3, then one add ----
      asm volatile("s_waitcnt vmcnt(0)" ::: "memory");
      if (l == 0) atomicAdd(arr_cp, 1u);
    }

    // prefetch next step's xin0 gather (tableV constant, L1-hot)
    if (w < 4 && it + 1 < 512) {
      const int xv = x[obg * 512 + it + 1];
#pragma unroll
      for (int g = 0; g < 4; ++g)
        tvh[g] = tableV[xv * 4096 + cg * 32 + ocb * 16 + g * 4 + ojj];
    }
  }
}

// ---------------------------------------------------------------- FC ----
__global__ __launch_bounds__(256, 2) void fc_kernel(
    const _Float16* __restrict__ hseq, const _Float16* __restrict__ fcwT,
    const float* __restrict__ fc_b, float* __restrict__ out) {
  __shared__ float hl[16][1024];      // 64 KB
  const int tid = threadIdx.x;
  const int t = blockIdx.x >> 2, bs = blockIdx.x & 3;
  const int v = tid & 127, hh = tid >> 7;

  // h2[t][b][u] lives at hseq buffer t+2, row b, halfs 1024..2047
  const h2v* hp = (const h2v*)hseq;
  const size_t base = (size_t)(t + 2) * 65536 + 512;
  for (int idx = tid; idx < 8192; idx += 256) {
    const int bl = idx >> 9, kp = idx & 511;
    const h2v pr = hp[base + (size_t)((bs * 16 + bl)) * 1024 + kp];
    hl[bl][2 * kp] = (float)pr.x;
    hl[bl][2 * kp + 1] = (float)pr.y;
  }
  __syncthreads();

  float acc[8];
#pragma unroll
  for (int i = 0; i < 8; ++i) acc[i] = 0.0f;
  const int bl0 = hh * 8;
#pragma unroll 1
  for (int k4 = 0; k4 < 256; ++k4) {
    const int k = k4 * 4;
    const float w0 = (float)fcwT[(k + 0) * 128 + v];
    const float w1 = (float)fcwT[(k + 1) * 128 + v];
    const float w2 = (float)fcwT[(k + 2) * 128 + v];
    const float w3 = (float)fcwT[(k + 3) * 128 + v];
#pragma unroll
    for (int i = 0; i < 8; ++i) {
      const float4 hv = *(const float4*)&hl[bl0 + i][k];
      acc[i] += hv.x * w0 + hv.y * w1 + hv.z * w2 + hv.w * w3;
    }
  }
  const float bias = fc_b[v];
#pragma unroll
  for (int i = 0; i < 8; ++i) {
    const int bb = bs * 16 + bl0 + i;
    out[(bb * 512 + t) * 128 + v] = acc[i] + bias;
  }
}

// ------------------------------------------------------------- launch ----
extern "C" void kernel_launch(void* const* d_in, const int* in_sizes, int n_in,
                              void* d_out, int out_size, void* d_ws,
                              size_t ws_size, hipStream_t stream) {
  const int* x = (const int*)d_in[0];
  const float* emb = (const float*)d_in[1];
  const float* w_ih0 = (const float*)d_in[2];
  const float* w_hh0 = (const float*)d_in[3];
  const float* b_ih0 = (const float*)d_in[4];
  const float* b_hh0 = (const float*)d_in[5];
  const float* w_ih1 = (const float*)d_in[6];
  const float* w_hh1 = (const float*)d_in[7];
  const float* b_ih1 = (const float*)d_in[8];
  const float* b_hh1 = (const float*)d_in[9];
  const float* fc_w = (const float*)d_in[10];
  const float* fc_b = (const float*)d_in[11];
  float* out = (float*)d_out;

  char* ws = (char*)d_ws;
  _Float16* tableV = (_Float16*)(ws);
  _Float16* fcwT = (_Float16*)(ws + 1048576);
  unsigned* bar = (unsigned*)(ws + 1310720);
  _Float16* hseq = (_Float16*)(ws + 1376256);   // 514 x 262144 B
  unsigned* zb = (unsigned*)(ws + 1376256);     // zero buffers 0,1

  prep_kernel<<<2593, 256, 0, stream>>>(emb, w_ih0, b_ih0, b_hh0, fc_w,
                                        tableV, fcwT, zb, bar);

  const _Float16* tableVc = tableV;
  _Float16* hseqa = hseq;
  unsigned* bara = bar;
  void* args[] = {(void*)&x,     (void*)&tableVc, (void*)&w_hh0,
                  (void*)&w_ih1, (void*)&w_hh1,   (void*)&b_ih1,
                  (void*)&b_hh1, (void*)&hseqa,   (void*)&bara};
  hipLaunchCooperativeKernel(lstm_mfma, dim3(256), dim3(768), args, 0, stream);

  fc_kernel<<<2048, 256, 0, stream>>>(hseq, fcwT, fc_b, out);
}

// Round 6
// 8073.046 us; speedup vs baseline: 1.3072x; 1.3072x over previous
//
#include <hip/hip_runtime.h>

// Shapes: VOCAB=128, EMBED=512, HIDDEN=1024, B=64, T=512. Inputs fp32, x int32.
// ws layout (bytes):
//   tableV : [128 vocab][4096 C] fp16   @ 0         (1 MB)  xin0+bias
//   fcwT   : [1024 k][128 v] fp16       @ 1048576   (256 KB)
//   bar    : [512 words] u32            @ 1310720   (2 KB)  counters
//   hseq   : [514 buf][64 b][2048 k]f16 @ 1376256   (128.5 MB) fresh h per step
//
// DUAL-STREAM INTERLEAVE (this round): the two m-halves (batch rows 0-31 and
// 32-63) are independent recurrences USING THE SAME WEIGHTS. R4 gave each
// its own 128 blocks (B-regs duplicated). Now: 128 blocks total, each holds
// B once and alternates per cycle: phase A = m0 step it, phase B = m1 step
// it. While phase A's h stores/signals propagate (store-ack + counter
// visibility + consumer L3 fetch ~1.5-2 us), the block computes phase B —
// exchange latency is overlapped by the sibling stream's compute instead of
// sitting serially in every step (R4's dominant residue: 8.5 us/step with
// every pipe <10% busy).
// Per-phase sync = EXACTLY R4's proven pattern (R5 lesson: do not increase
// same-address atomic fan-in or poller count): tid0-only polls min of 8
// words; 16 tid0-adds per word per cycle; separate word sets per stream
// (m word base = m*128 u32). zs per stream (2 x 48 KB = 96 KB LDS).
//
// FRESH-BUFFER h EXCHANGE (R1, kept): step it reads buffer it, writes buffer
// it+1. Consumer XCD never touched buffer it+1 before its poll passes, so L2
// cannot hold a stale line -> h loads are PLAIN CACHED dwordx4. Stores are
// agent-scope relaxed atomics (write-through at the L3 coherence point) +
// s_waitcnt vmcnt(0) before the signal add. Line-ownership: cg =
// (blk&7)*16 + (blk>>3) ==> every 128-B h line is written only by ONE XCD
// (blk%8 == XCD round-robin heuristic, 128 blocks = 16/XCD).
// buffer[t+2][b][1024+u] IS h2[t] -> FC reads hseq directly.
//
// SWIZZLED LDS REDUCTION (R4, kept): zs[m][w][r][rq][col32],
// col32 = (cb*16 + colp) ^ ((rq&1)<<4), colp = j*4+g; 2-way max on writes,
// aligned b128 owner reads (bank conflicts 2.0e8 -> 2.5e7 measured).
// Transcendentals: __expf + division only (proven on this harness).
//
// Block (128 total): col-group cg = (blk&7)*16 + (blk>>3) (units cg*8..+8 of
// BOTH layers, BOTH m-halves). Wave w (12/block): layer = w<4 ? 0 : 1,
// K-chunk kc (256 halfs); B in REGISTERS, loaded once, used by both phases.
// Per phase: A (2 16-row tiles of that m) x B -> C-tiles -> LDS -> owner
// reduction (waves 0-3 layer0 cells, 4-7 layer1 cells) -> h store -> signal.

typedef _Float16 v8h __attribute__((ext_vector_type(8)));
typedef _Float16 v4h __attribute__((ext_vector_type(4)));
typedef float v4f __attribute__((ext_vector_type(4)));
typedef _Float16 h2v __attribute__((ext_vector_type(2)));
typedef unsigned long long u64t;

__device__ __forceinline__ float sigf(float x) {
  return 1.0f / (1.0f + __expf(-x));
}
__device__ __forceinline__ float tanhfast(float x) {
  // tanh = 1 - 2/(e^{2x}+1); graceful at +-inf (__expf -> inf/0)
  return 1.0f - 2.0f / (1.0f + __expf(2.0f * x));
}

__device__ __forceinline__ void pollbar(const unsigned* base, unsigned tgt) {
  for (;;) {
    unsigned mn = 0xffffffffu;
#pragma unroll
    for (int g = 0; g < 8; ++g) {
      const unsigned vv = __hip_atomic_load(base + g * 16, __ATOMIC_RELAXED,
                                            __HIP_MEMORY_SCOPE_AGENT);
      mn = vv < mn ? vv : mn;
    }
    if (mn >= tgt) break;
    __builtin_amdgcn_s_sleep(1);
  }
}

// ---------------------------------------------------------------- prep ----
__global__ __launch_bounds__(256) void prep_kernel(
    const float* __restrict__ emb, const float* __restrict__ w_ih0,
    const float* __restrict__ b_ih0, const float* __restrict__ b_hh0,
    const float* __restrict__ fc_w, _Float16* __restrict__ tableV,
    _Float16* __restrict__ fcwT, unsigned* __restrict__ zbuf,
    unsigned* __restrict__ bar) {
  const int blk = blockIdx.x, tid = threadIdx.x;
  if (blk < 2048) {
    // tableV[v][C] = emb[v]·w_ih0[row(C)] + b_ih0[row] + b_hh0[row]
    const int C = blk * 2 + (tid >> 7);
    const int v = tid & 127;
    const int row =
        ((C >> 2) & 3) * 1024 + (C >> 5) * 8 + ((C >> 4) & 1) * 4 + (C & 3);
    float acc = b_ih0[row] + b_hh0[row];
    const float* er = emb + v * 512;
    const float* wr = w_ih0 + row * 512;
#pragma unroll 4
    for (int k = 0; k < 512; ++k) acc = fmaf(er[k], wr[k], acc);
    tableV[v * 4096 + C] = (_Float16)acc;
  } else if (blk < 2560) {
    const int idx = (blk - 2048) * 256 + tid;   // [0, 131072)
    const int v = idx & 127, k = idx >> 7;
    fcwT[k * 128 + v] = (_Float16)fc_w[v * 1024 + k];
  } else if (blk < 2592) {
    // zero hseq buffers 0 and 1 (step-0/1 initial h state): 131072 dwords
    const int idx = (blk - 2560) * 256 + tid;
#pragma unroll
    for (int q = 0; q < 16; ++q) zbuf[idx * 16 + q] = 0u;
  } else {
    for (int i = tid; i < 512; i += 256) bar[i] = 0u;
  }
}

// ---- one recurrence phase (stream MM, cell state CST, gather regs TVH) ----
#define PHASE(MM, CST, TVH)                                                    \
  do {                                                                         \
    float* const zsp = zs + (MM) * ZSZ;                                        \
    const int obgp = (MM) * 32 + ob;                                           \
    if (tid == 0) pollbar(bar + (MM) * 128, 16u * (unsigned)it);               \
    __syncthreads();                                                           \
    asm volatile("" ::: "memory");                                             \
    const _Float16* hr = hseq + (size_t)it * 131072;                           \
    _Float16* hw = hseq + (size_t)(it + 1) * 131072;                           \
    v4f a00 = {0, 0, 0, 0}, a01 = {0, 0, 0, 0};                                \
    v4f a10 = {0, 0, 0, 0}, a11 = {0, 0, 0, 0};                                \
    const bool active = (w < 4) ? (it < 512) : (it >= 1);                      \
    if (active) {                                                              \
      const _Float16* a0p =                                                    \
          hr + ((MM) * 32 + lane16) * 2048 + kc * 256 + quad * 8;              \
      const _Float16* a1p = a0p + 16 * 2048;                                   \
      v8h A0[8], A1[8];                                                        \
      _Pragma("unroll") for (int kk = 0; kk < 8; ++kk)                         \
          A0[kk] = *(const v8h*)(a0p + kk * 32);                               \
      _Pragma("unroll") for (int kk = 0; kk < 8; ++kk)                         \
          A1[kk] = *(const v8h*)(a1p + kk * 32);                               \
      _Pragma("unroll") for (int kk = 0; kk < 8; ++kk) {                       \
        a00 = __builtin_amdgcn_mfma_f32_16x16x32_f16(A0[kk], breg0[kk], a00,   \
                                                     0, 0, 0);                 \
        a10 = __builtin_amdgcn_mfma_f32_16x16x32_f16(A0[kk], breg1[kk], a10,   \
                                                     0, 0, 0);                 \
      }                                                                        \
      _Pragma("unroll") for (int kk = 0; kk < 8; ++kk) {                       \
        a01 = __builtin_amdgcn_mfma_f32_16x16x32_f16(A1[kk], breg0[kk], a01,   \
                                                     0, 0, 0);                 \
        a11 = __builtin_amdgcn_mfma_f32_16x16x32_f16(A1[kk], breg1[kk], a11,   \
                                                     0, 0, 0);                 \
      }                                                                        \
    }                                                                          \
    _Pragma("unroll") for (int r = 0; r < 4; ++r) {                            \
      float* zp = &zsp[((w * 4 + r) * 8 + quad) * 32];                         \
      zp[cswz] = a00[r];                                                       \
      zp[128 + cswz] = a01[r];                                                 \
      zp[cswz ^ 16] = a10[r];                                                  \
      zp[128 + (cswz ^ 16)] = a11[r];                                          \
    }                                                                          \
    __syncthreads();                                                           \
    const bool do0 = (w < 4) && (it < 512);                                    \
    const bool do1 = (w >= 4 && w < 8) && (it >= 1);                           \
    if (do0 || do1) {                                                          \
      v4f z;                                                                   \
      if (do0) {                                                               \
        z[0] = (float)TVH[0]; z[1] = (float)TVH[1];                            \
        z[2] = (float)TVH[2]; z[3] = (float)TVH[3];                            \
        _Pragma("unroll") for (int wv = 0; wv < 4; ++wv)                       \
            z += *(const v4f*)&zsp[((wv * 4 + rr) * 8 + rqo) * 32 + rcol];     \
      } else {                                                                 \
        z = bias4;                                                             \
        _Pragma("unroll") for (int wv = 4; wv < 12; ++wv)                      \
            z += *(const v4f*)&zsp[((wv * 4 + rr) * 8 + rqo) * 32 + rcol];     \
      }                                                                        \
      const float ig = sigf(z[0]), fg = sigf(z[1]);                            \
      const float gg = tanhfast(z[2]), og = sigf(z[3]);                        \
      CST = fg * CST + ig * gg;                                                \
      const float hv = og * tanhfast(CST);                                     \
      const unsigned hu =                                                      \
          (unsigned)__builtin_bit_cast(unsigned short, (_Float16)hv);          \
      const unsigned p1 = (unsigned)__shfl_xor((int)hu, 1, 64);                \
      const unsigned lo = (oj & 1) ? ((p1 & 0xffffu) | (hu << 16))             \
                                   : ((hu & 0xffffu) | (p1 << 16));            \
      const unsigned p2 = (unsigned)__shfl_xor((int)lo, 2, 64);                \
      if ((oj & 3) == 0) {                                                     \
        const u64t val = (u64t)lo | ((u64t)p2 << 32);                          \
        if (do0) {                                                             \
          __hip_atomic_store((u64t*)(hw + obgp * 2048 + cg * 8 + oj), val,     \
                             __ATOMIC_RELAXED, __HIP_MEMORY_SCOPE_AGENT);      \
        } else {                                                               \
          __hip_atomic_store((u64t*)(hw + obgp * 2048 + 1024 + cg * 8 + oj),   \
                             val, __ATOMIC_RELAXED, __HIP_MEMORY_SCOPE_AGENT); \
        }                                                                      \
      }                                                                        \
    }                                                                          \
    if (w < 4 && it + 1 < 512) {                                               \
      const int xv = x[obgp * 512 + it + 1];                                   \
      _Pragma("unroll") for (int g = 0; g < 4; ++g)                            \
          TVH[g] = tableV[xv * 4096 + cg * 32 + ocb * 16 + g * 4 + ojj];       \
    }                                                                          \
    asm volatile("s_waitcnt vmcnt(0)" ::: "memory");                           \
    __syncthreads();                                                           \
    if (tid == 0 && it < 512) atomicAdd(&bar[((MM) * 8 + gq) * 16], 1u);       \
  } while (0)

// ------------------------------------------------------------ recurrent ----
__global__ __launch_bounds__(768, 1) void lstm_mfma(
    const int* __restrict__ x, const _Float16* __restrict__ tableV,
    const float* __restrict__ w_hh0, const float* __restrict__ w_ih1,
    const float* __restrict__ w_hh1, const float* __restrict__ b_ih1,
    const float* __restrict__ b_hh1, _Float16* __restrict__ hseq,
    unsigned* __restrict__ bar) {
  // per-stream: [wave12][r4][rq8][col32] floats = 48 KB; x2 streams = 96 KB
  __shared__ __align__(16) float zs[2 * 12 * 4 * 8 * 32];
  const int ZSZ = 12 * 4 * 8 * 32;

  const int tid = threadIdx.x, blk = blockIdx.x;
  const int w = tid >> 6, l = tid & 63;
  const int lane16 = l & 15, quad = l >> 4;
  // XCD-local cg grouping (128 blocks = 16/XCD under %8 round-robin)
  const int cg = (blk & 7) * 16 + (blk >> 3);
  const int kc = (w < 4) ? w : (w - 4);
  const int gq = blk & 7;   // signal word within each stream's set

  // --- stage B-fragments into REGISTERS (once; shared by both streams) ---
  v8h breg0[8], breg1[8];
  {
    const int g = lane16 >> 2, j = lane16 & 3;
    const float* Wsrc;
    int kbase;
    if (w < 4) {
      Wsrc = w_hh0;
      kbase = kc * 256;
    } else {
      const int kcomb = kc * 256;
      if (kcomb < 1024) {
        Wsrc = w_ih1;
        kbase = kcomb;
      } else {
        Wsrc = w_hh1;
        kbase = kcomb - 1024;
      }
    }
#pragma unroll
    for (int cb = 0; cb < 2; ++cb) {
      const int row = g * 1024 + cg * 8 + cb * 4 + j;
      const float* rp = Wsrc + row * 1024 + kbase + quad * 8;
#pragma unroll
      for (int kk = 0; kk < 8; ++kk) {
        const float4 f0 = *(const float4*)(rp + kk * 32);
        const float4 f1 = *(const float4*)(rp + kk * 32 + 4);
        v8h b;
        b[0] = (_Float16)f0.x; b[1] = (_Float16)f0.y;
        b[2] = (_Float16)f0.z; b[3] = (_Float16)f0.w;
        b[4] = (_Float16)f1.x; b[5] = (_Float16)f1.y;
        b[6] = (_Float16)f1.z; b[7] = (_Float16)f1.w;
        if (cb == 0) breg0[kk] = b; else breg1[kk] = b;
      }
    }
  }

  // --- elementwise-owner constants (m-independent) ---
  const int oj = l & 7, ojj = l & 3, ocb = (l >> 2) & 1;
  const int ob = (w & 3) * 8 + (l >> 3);
  // swizzle constants
  const int colp = (lane16 & 3) * 4 + (lane16 >> 2);      // j*4+g
  const int cswz = colp ^ ((quad & 1) << 4);              // write col, cb=0
  const int rr = ob & 3, rqo = ob >> 2;                   // owner row split
  const int rcol = (ocb * 16 + ojj * 4) ^ ((rqo & 1) << 4);  // owner read col

  v4f bias4 = {0.f, 0.f, 0.f, 0.f};
  if (w >= 4 && w < 8) {
#pragma unroll
    for (int g = 0; g < 4; ++g) {
      const int row = g * 1024 + cg * 8 + ocb * 4 + ojj;
      bias4[g] = b_ih1[row] + b_hh1[row];
    }
  }
  v4h tvh0 = {0, 0, 0, 0}, tvh1 = {0, 0, 0, 0};
  if (w < 4) {
    const int xv0 = x[(0 * 32 + ob) * 512];
    const int xv1 = x[(1 * 32 + ob) * 512];
#pragma unroll
    for (int g = 0; g < 4; ++g) {
      tvh0[g] = tableV[xv0 * 4096 + cg * 32 + ocb * 16 + g * 4 + ojj];
      tvh1[g] = tableV[xv1 * 4096 + cg * 32 + ocb * 16 + g * 4 + ojj];
    }
  }

  float cst0 = 0.0f, cst1 = 0.0f;

  for (int it = 0; it <= 512; ++it) {
    PHASE(0, cst0, tvh0);   // stream m0: rows 0-31
    PHASE(1, cst1, tvh1);   // stream m1: rows 32-63 (covers m0's exchange)
  }
}

// ---------------------------------------------------------------- FC ----
__global__ __launch_bounds__(256, 2) void fc_kernel(
    const _Float16* __restrict__ hseq, const _Float16* __restrict__ fcwT,
    const float* __restrict__ fc_b, float* __restrict__ out) {
  __shared__ float hl[16][1024];      // 64 KB
  const int tid = threadIdx.x;
  const int t = blockIdx.x >> 2, bs = blockIdx.x & 3;
  const int v = tid & 127, hh = tid >> 7;

  // h2[t][b][u] lives at hseq buffer t+2, row b, halfs 1024..2047
  const h2v* hp = (const h2v*)hseq;
  const size_t base = (size_t)(t + 2) * 65536 + 512;
  for (int idx = tid; idx < 8192; idx += 256) {
    const int bl = idx >> 9, kp = idx & 511;
    const h2v pr = hp[base + (size_t)((bs * 16 + bl)) * 1024 + kp];
    hl[bl][2 * kp] = (float)pr.x;
    hl[bl][2 * kp + 1] = (float)pr.y;
  }
  __syncthreads();

  float acc[8];
#pragma unroll
  for (int i = 0; i < 8; ++i) acc[i] = 0.0f;
  const int bl0 = hh * 8;
#pragma unroll 1
  for (int k4 = 0; k4 < 256; ++k4) {
    const int k = k4 * 4;
    const float w0 = (float)fcwT[(k + 0) * 128 + v];
    const float w1 = (float)fcwT[(k + 1) * 128 + v];
    const float w2 = (float)fcwT[(k + 2) * 128 + v];
    const float w3 = (float)fcwT[(k + 3) * 128 + v];
#pragma unroll
    for (int i = 0; i < 8; ++i) {
      const float4 hv = *(const float4*)&hl[bl0 + i][k];
      acc[i] += hv.x * w0 + hv.y * w1 + hv.z * w2 + hv.w * w3;
    }
  }
  const float bias = fc_b[v];
#pragma unroll
  for (int i = 0; i < 8; ++i) {
    const int bb = bs * 16 + bl0 + i;
    out[(bb * 512 + t) * 128 + v] = acc[i] + bias;
  }
}

// ------------------------------------------------------------- launch ----
extern "C" void kernel_launch(void* const* d_in, const int* in_sizes, int n_in,
                              void* d_out, int out_size, void* d_ws,
                              size_t ws_size, hipStream_t stream) {
  const int* x = (const int*)d_in[0];
  const float* emb = (const float*)d_in[1];
  const float* w_ih0 = (const float*)d_in[2];
  const float* w_hh0 = (const float*)d_in[3];
  const float* b_ih0 = (const float*)d_in[4];
  const float* b_hh0 = (const float*)d_in[5];
  const float* w_ih1 = (const float*)d_in[6];
  const float* w_hh1 = (const float*)d_in[7];
  const float* b_ih1 = (const float*)d_in[8];
  const float* b_hh1 = (const float*)d_in[9];
  const float* fc_w = (const float*)d_in[10];
  const float* fc_b = (const float*)d_in[11];
  float* out = (float*)d_out;

  char* ws = (char*)d_ws;
  _Float16* tableV = (_Float16*)(ws);
  _Float16* fcwT = (_Float16*)(ws + 1048576);
  unsigned* bar = (unsigned*)(ws + 1310720);
  _Float16* hseq = (_Float16*)(ws + 1376256);   // 514 x 262144 B
  unsigned* zb = (unsigned*)(ws + 1376256);     // zero buffers 0,1

  prep_kernel<<<2593, 256, 0, stream>>>(emb, w_ih0, b_ih0, b_hh0, fc_w,
                                        tableV, fcwT, zb, bar);

  const _Float16* tableVc = tableV;
  _Float16* hseqa = hseq;
  unsigned* bara = bar;
  void* args[] = {(void*)&x,     (void*)&tableVc, (void*)&w_hh0,
                  (void*)&w_ih1, (void*)&w_hh1,   (void*)&b_ih1,
                  (void*)&b_hh1, (void*)&hseqa,   (void*)&bara};
  hipLaunchCooperativeKernel(lstm_mfma, dim3(128), dim3(768), args, 0, stream);

  fc_kernel<<<2048, 256, 0, stream>>>(hseq, fcwT, fc_b, out);
}

// Round 7
// 4878.344 us; speedup vs baseline: 2.1633x; 1.6549x over previous
//
#include <hip/hip_runtime.h>

// Shapes: VOCAB=128, EMBED=512, HIDDEN=1024, B=64, T=512. Inputs fp32, x int32.
// ws layout (bytes):
//   tableV : [128 vocab][4096 C] fp16   @ 0         (1 MB)  xin0+bias
//   fcwT   : [1024 k][128 v] fp16       @ 1048576   (256 KB)
//   bar    : [512 words] u32            @ 1310720   (2 KB)  flat barrier
//   hseq   : [514 buf][64 b][2048 k]f16 @ 1376256   (128.5 MB) fresh h per step
//
// Structure = R4 (best measured: 4360 us), ONE change this round:
//
// ALL-LOADS-IN-FLIGHT (R7): R6's dual-phase probe showed the per-step cost
// is a ~7 us IN-BLOCK serial chain, not barrier latency. At VGPR_Count=76
// the compiler cannot keep A0[8]+A1[8] (64 VGPR) live, so it interleaves
// load->waitcnt->MFMA in small windows = ~4-8 serialized memory latencies
// (half HBM-class: write-through stores don't allocate in L3 -> first
// touch per XCD fetches HBM; FETCH_SIZE = 4x unique confirms). Fix: stage
// the full A0/A1 arrays, then sched_barrier(0) so the scheduler cannot
// sink loads below MFMAs; regalloc must keep 16 loads in flight (~140
// VGPR, still fine at 12 waves/block, 1 block/CU). Expect VGPR ~130-150
// and the load chain to collapse to ~1 latency.
//
// FRESH-BUFFER h EXCHANGE (R1): step it reads buffer it, writes buffer
// it+1; consumer XCD never touched buffer it+1 before step it+1 -> plain
// cached dwordx4 loads are coherent. Stores agent-scope relaxed atomics +
// vmcnt(0) before arrival. Line-ownership: cg = (blk&7)*16+t.
// buffer[t+2][b][1024+u] IS h2[t] -> FC reads hseq directly.
// FLAT m-SPLIT BARRIER (R2): two independent single-stage barriers, arrival
// adds spread over 8 words, tid0 polls min-of-8. (R5 lesson: never increase
// same-address atomic fan-in or poller count.)
// SWIZZLED LDS REDUCTION (R4): zs[w][r][rq][col32], col32 = (cb*16+colp)^
// ((rq&1)<<4), colp=j*4+g; 2-way max write conflicts, b128 owner reads
// (conflicts 2.0e8 -> 2.5e7 measured). Transcendentals: __expf + division.
//
// Block (256 = 2 m x 128 cg): M-half m (rows m*32..+32), col-group cg
// (units cg*8..+8 of BOTH layers). Wave w (12/block): layer = w<4 ? 0 : 1,
// K-chunk kc = w<4 ? w : w-4 (256 halfs); B in REGISTERS; A loaded once,
// used twice (cb=0,1). C-tiles -> LDS -> owner reduction (waves 0-3 layer0
// cells, 4-7 layer1 cells).

typedef _Float16 v8h __attribute__((ext_vector_type(8)));
typedef float v4f __attribute__((ext_vector_type(4)));
typedef _Float16 h2v __attribute__((ext_vector_type(2)));
typedef unsigned long long u64t;

__device__ __forceinline__ float sigf(float x) {
  return 1.0f / (1.0f + __expf(-x));
}
__device__ __forceinline__ float tanhfast(float x) {
  // tanh = 1 - 2/(e^{2x}+1); graceful at +-inf (__expf -> inf/0)
  return 1.0f - 2.0f / (1.0f + __expf(2.0f * x));
}

// ---------------------------------------------------------------- prep ----
__global__ __launch_bounds__(256) void prep_kernel(
    const float* __restrict__ emb, const float* __restrict__ w_ih0,
    const float* __restrict__ b_ih0, const float* __restrict__ b_hh0,
    const float* __restrict__ fc_w, _Float16* __restrict__ tableV,
    _Float16* __restrict__ fcwT, unsigned* __restrict__ zbuf,
    unsigned* __restrict__ bar) {
  const int blk = blockIdx.x, tid = threadIdx.x;
  if (blk < 2048) {
    // tableV[v][C] = emb[v]·w_ih0[row(C)] + b_ih0[row] + b_hh0[row]
    const int C = blk * 2 + (tid >> 7);
    const int v = tid & 127;
    const int row =
        ((C >> 2) & 3) * 1024 + (C >> 5) * 8 + ((C >> 4) & 1) * 4 + (C & 3);
    float acc = b_ih0[row] + b_hh0[row];
    const float* er = emb + v * 512;
    const float* wr = w_ih0 + row * 512;
#pragma unroll 4
    for (int k = 0; k < 512; ++k) acc = fmaf(er[k], wr[k], acc);
    tableV[v * 4096 + C] = (_Float16)acc;
  } else if (blk < 2560) {
    const int idx = (blk - 2048) * 256 + tid;   // [0, 131072)
    const int v = idx & 127, k = idx >> 7;
    fcwT[k * 128 + v] = (_Float16)fc_w[v * 1024 + k];
  } else if (blk < 2592) {
    // zero hseq buffers 0 and 1 (step-0/1 initial h state): 131072 dwords
    const int idx = (blk - 2560) * 256 + tid;
#pragma unroll
    for (int q = 0; q < 16; ++q) zbuf[idx * 16 + q] = 0u;
  } else {
    for (int i = tid; i < 512; i += 256) bar[i] = 0u;
  }
}

// ------------------------------------------------------------ recurrent ----
__global__ __launch_bounds__(768, 1) void lstm_mfma(
    const int* __restrict__ x, const _Float16* __restrict__ tableV,
    const float* __restrict__ w_hh0, const float* __restrict__ w_ih1,
    const float* __restrict__ w_hh1, const float* __restrict__ b_ih1,
    const float* __restrict__ b_hh1, _Float16* __restrict__ hseq,
    unsigned* __restrict__ bar) {
  // [wave12][r4][rq8][col32] floats, col32 = (cb*16+colp)^((rq&1)<<4): 48 KB
  __shared__ __align__(16) float zs[12 * 4 * 8 * 32];

  const int tid = threadIdx.x, blk = blockIdx.x;
  const int w = tid >> 6, l = tid & 63;
  const int lane16 = l & 15, quad = l >> 4;
  // XCD-local cg grouping: all 8 writer-blocks of any 128-B h line share
  // blk&7 (== XCD under the %8 round-robin dispatch).
  const int xcd = blk & 7, bidx = blk >> 3;
  const int m = bidx >> 4, cg = xcd * 16 + (bidx & 15);
  const int kc = (w < 4) ? w : (w - 4);

  // --- stage B-fragments into REGISTERS (once) ---
  v8h breg0[8], breg1[8];
  {
    const int g = lane16 >> 2, j = lane16 & 3;
    const float* Wsrc;
    int kbase;
    if (w < 4) {
      Wsrc = w_hh0;
      kbase = kc * 256;
    } else {
      const int kcomb = kc * 256;
      if (kcomb < 1024) {
        Wsrc = w_ih1;
        kbase = kcomb;
      } else {
        Wsrc = w_hh1;
        kbase = kcomb - 1024;
      }
    }
#pragma unroll
    for (int cb = 0; cb < 2; ++cb) {
      const int row = g * 1024 + cg * 8 + cb * 4 + j;
      const float* rp = Wsrc + row * 1024 + kbase + quad * 8;
#pragma unroll
      for (int kk = 0; kk < 8; ++kk) {
        const float4 f0 = *(const float4*)(rp + kk * 32);
        const float4 f1 = *(const float4*)(rp + kk * 32 + 4);
        v8h b;
        b[0] = (_Float16)f0.x; b[1] = (_Float16)f0.y;
        b[2] = (_Float16)f0.z; b[3] = (_Float16)f0.w;
        b[4] = (_Float16)f1.x; b[5] = (_Float16)f1.y;
        b[6] = (_Float16)f1.z; b[7] = (_Float16)f1.w;
        if (cb == 0) breg0[kk] = b; else breg1[kk] = b;
      }
    }
  }

  // --- elementwise-owner constants ---
  const int oj = l & 7, ojj = l & 3, ocb = (l >> 2) & 1;
  const int ob = (w & 3) * 8 + (l >> 3);
  const int obg = m * 32 + ob;
  // swizzle constants
  const int colp = (lane16 & 3) * 4 + (lane16 >> 2);      // j*4+g
  const int cswz = colp ^ ((quad & 1) << 4);              // write col, cb=0
  const int rr = ob & 3, rqo = ob >> 2;                   // owner row split
  const int rcol = (ocb * 16 + ojj * 4) ^ ((rqo & 1) << 4);  // owner read col

  v4f bias4 = {0.f, 0.f, 0.f, 0.f};
  if (w >= 4 && w < 8) {
#pragma unroll
    for (int g = 0; g < 4; ++g) {
      const int row = g * 1024 + cg * 8 + ocb * 4 + ojj;
      bias4[g] = b_ih1[row] + b_hh1[row];
    }
  }
  _Float16 tvh[4] = {0, 0, 0, 0};
  if (w < 4) {
    const int xv = x[obg * 512];
#pragma unroll
    for (int g = 0; g < 4; ++g)
      tvh[g] = tableV[xv * 4096 + cg * 32 + ocb * 16 + g * 4 + ojj];
  }

  float cst = 0.0f;
  const int gq = blk & 7;   // arrival word within this m-half

  for (int it = 0; it <= 512; ++it) {
    const _Float16* hr = hseq + (size_t)it * 131072;       // fresh buffers
    _Float16* hw = hseq + (size_t)(it + 1) * 131072;

    v4f a00 = {0, 0, 0, 0}, a01 = {0, 0, 0, 0};
    v4f a10 = {0, 0, 0, 0}, a11 = {0, 0, 0, 0};
    const bool active = (w < 4) ? (it < 512) : (it >= 1);
    if (active) {
      // A: rows m*32 + mt*16 + lane16, halfs kc*256 + kk*32 + quad*8
      // PLAIN CACHED loads: buffer `it` address is fresh for this XCD's L2
      // (or holds only same-XCD write-through lines) -> always coherent.
      const _Float16* a0p = hr + (m * 32 + lane16) * 2048 + kc * 256 + quad * 8;
      const _Float16* a1p = a0p + 16 * 2048;
      v8h A0[8], A1[8];
#pragma unroll
      for (int kk = 0; kk < 8; ++kk) A0[kk] = *(const v8h*)(a0p + kk * 32);
#pragma unroll
      for (int kk = 0; kk < 8; ++kk) A1[kk] = *(const v8h*)(a1p + kk * 32);
      // R7: pin all 16 loads ABOVE the MFMA stream. Without this the
      // scheduler sinks loads into the MFMA sequence in ~4-reg windows
      // (VGPR_Count 76) => 4-8 serialized memory latencies per step.
      __builtin_amdgcn_sched_barrier(0);
#pragma unroll
      for (int kk = 0; kk < 8; ++kk) {
        a00 = __builtin_amdgcn_mfma_f32_16x16x32_f16(A0[kk], breg0[kk], a00, 0, 0, 0);
        a10 = __builtin_amdgcn_mfma_f32_16x16x32_f16(A0[kk], breg1[kk], a10, 0, 0, 0);
      }
#pragma unroll
      for (int kk = 0; kk < 8; ++kk) {
        a01 = __builtin_amdgcn_mfma_f32_16x16x32_f16(A1[kk], breg0[kk], a01, 0, 0, 0);
        a11 = __builtin_amdgcn_mfma_f32_16x16x32_f16(A1[kk], breg1[kk], a11, 0, 0, 0);
      }
    }

    // C-tiles -> LDS, swizzled (R4 layout). Banks: 2-way max on writes.
#pragma unroll
    for (int r = 0; r < 4; ++r) {
      float* zp = &zs[((w * 4 + r) * 8 + quad) * 32];
      zp[cswz] = a00[r];
      zp[128 + cswz] = a01[r];
      zp[cswz ^ 16] = a10[r];
      zp[128 + (cswz ^ 16)] = a11[r];
    }
    __syncthreads();

    // owner reduction + cell update (vector b128 reads, gates contiguous)
    const bool do0 = (w < 4) && (it < 512);
    const bool do1 = (w >= 4 && w < 8) && (it >= 1);
    if (do0 || do1) {
      v4f z;
      if (do0) {
        z[0] = (float)tvh[0]; z[1] = (float)tvh[1];
        z[2] = (float)tvh[2]; z[3] = (float)tvh[3];
#pragma unroll
        for (int wv = 0; wv < 4; ++wv)
          z += *(const v4f*)&zs[((wv * 4 + rr) * 8 + rqo) * 32 + rcol];
      } else {
        z = bias4;
#pragma unroll
        for (int wv = 4; wv < 12; ++wv)
          z += *(const v4f*)&zs[((wv * 4 + rr) * 8 + rqo) * 32 + rcol];
      }
      const float ig = sigf(z[0]), fg = sigf(z[1]);
      const float gg = tanhfast(z[2]), og = sigf(z[3]);
      cst = fg * cst + ig * gg;
      const float hv = og * tanhfast(cst);

      // pack 8 unit-lanes (same b) -> two 8-B stores (lanes oj==0, oj==4)
      const unsigned hu =
          (unsigned)__builtin_bit_cast(unsigned short, (_Float16)hv);
      const unsigned p1 = (unsigned)__shfl_xor((int)hu, 1, 64);
      const unsigned lo = (oj & 1) ? ((p1 & 0xffffu) | (hu << 16))
                                   : ((hu & 0xffffu) | (p1 << 16));
      const unsigned p2 = (unsigned)__shfl_xor((int)lo, 2, 64);
      if ((oj & 3) == 0) {
        const u64t val = (u64t)lo | ((u64t)p2 << 32);
        if (do0) {
          __hip_atomic_store((u64t*)(hw + obg * 2048 + cg * 8 + oj), val,
                             __ATOMIC_RELAXED, __HIP_MEMORY_SCOPE_AGENT);
        } else {
          __hip_atomic_store((u64t*)(hw + obg * 2048 + 1024 + cg * 8 + oj),
                             val, __ATOMIC_RELAXED, __HIP_MEMORY_SCOPE_AGENT);
        }
      }
    }

    // prefetch next step's xin0 gather (tableV constant, L1-hot)
    if (w < 4 && it + 1 < 512) {
      const int xv = x[obg * 512 + it + 1];
#pragma unroll
      for (int g = 0; g < 4; ++g)
        tvh[g] = tableV[xv * 4096 + cg * 32 + ocb * 16 + g * 4 + ojj];
    }

    if (it < 512) {
      // ---- flat m-split barrier: one add, one poll stage, no leaders ----
      asm volatile("s_waitcnt vmcnt(0)" ::: "memory");  // h stores at L3
      __syncthreads();
      if (tid == 0) {
        atomicAdd(&bar[(m * 8 + gq) * 16], 1u);         // fire-and-forget
        const unsigned tgt = 16u * (unsigned)(it + 1);
        for (;;) {
          unsigned v[8];
#pragma unroll
          for (int g = 0; g < 8; ++g)
            v[g] = __hip_atomic_load(&bar[(m * 8 + g) * 16], __ATOMIC_RELAXED,
                                     __HIP_MEMORY_SCOPE_AGENT);
          unsigned mn = v[0];
#pragma unroll
          for (int g = 1; g < 8; ++g) mn = (v[g] < mn) ? v[g] : mn;
          if (mn >= tgt) break;
          __builtin_amdgcn_s_sleep(1);
        }
      }
      __syncthreads();
      // keep the fresh-buffer plain loads from being hoisted above release
      asm volatile("" ::: "memory");
    }
  }
}

// ---------------------------------------------------------------- FC ----
__global__ __launch_bounds__(256, 2) void fc_kernel(
    const _Float16* __restrict__ hseq, const _Float16* __restrict__ fcwT,
    const float* __restrict__ fc_b, float* __restrict__ out) {
  __shared__ float hl[16][1024];      // 64 KB
  const int tid = threadIdx.x;
  const int t = blockIdx.x >> 2, bs = blockIdx.x & 3;
  const int v = tid & 127, hh = tid >> 7;

  // h2[t][b][u] lives at hseq buffer t+2, row b, halfs 1024..2047
  const h2v* hp = (const h2v*)hseq;
  const size_t base = (size_t)(t + 2) * 65536 + 512;
  for (int idx = tid; idx < 8192; idx += 256) {
    const int bl = idx >> 9, kp = idx & 511;
    const h2v pr = hp[base + (size_t)((bs * 16 + bl)) * 1024 + kp];
    hl[bl][2 * kp] = (float)pr.x;
    hl[bl][2 * kp + 1] = (float)pr.y;
  }
  __syncthreads();

  float acc[8];
#pragma unroll
  for (int i = 0; i < 8; ++i) acc[i] = 0.0f;
  const int bl0 = hh * 8;
#pragma unroll 1
  for (int k4 = 0; k4 < 256; ++k4) {
    const int k = k4 * 4;
    const float w0 = (float)fcwT[(k + 0) * 128 + v];
    const float w1 = (float)fcwT[(k + 1) * 128 + v];
    const float w2 = (float)fcwT[(k + 2) * 128 + v];
    const float w3 = (float)fcwT[(k + 3) * 128 + v];
#pragma unroll
    for (int i = 0; i < 8; ++i) {
      const float4 hv = *(const float4*)&hl[bl0 + i][k];
      acc[i] += hv.x * w0 + hv.y * w1 + hv.z * w2 + hv.w * w3;
    }
  }
  const float bias = fc_b[v];
#pragma unroll
  for (int i = 0; i < 8; ++i) {
    const int bb = bs * 16 + bl0 + i;
    out[(bb * 512 + t) * 128 + v] = acc[i] + bias;
  }
}

// ------------------------------------------------------------- launch ----
extern "C" void kernel_launch(void* const* d_in, const int* in_sizes, int n_in,
                              void* d_out, int out_size, void* d_ws,
                              size_t ws_size, hipStream_t stream) {
  const int* x = (const int*)d_in[0];
  const float* emb = (const float*)d_in[1];
  const float* w_ih0 = (const float*)d_in[2];
  const float* w_hh0 = (const float*)d_in[3];
  const float* b_ih0 = (const float*)d_in[4];
  const float* b_hh0 = (const float*)d_in[5];
  const float* w_ih1 = (const float*)d_in[6];
  const float* w_hh1 = (const float*)d_in[7];
  const float* b_ih1 = (const float*)d_in[8];
  const float* b_hh1 = (const float*)d_in[9];
  const float* fc_w = (const float*)d_in[10];
  const float* fc_b = (const float*)d_in[11];
  float* out = (float*)d_out;

  char* ws = (char*)d_ws;
  _Float16* tableV = (_Float16*)(ws);
  _Float16* fcwT = (_Float16*)(ws + 1048576);
  unsigned* bar = (unsigned*)(ws + 1310720);
  _Float16* hseq = (_Float16*)(ws + 1376256);   // 514 x 262144 B
  unsigned* zb = (unsigned*)(ws + 1376256);     // zero buffers 0,1

  prep_kernel<<<2593, 256, 0, stream>>>(emb, w_ih0, b_ih0, b_hh0, fc_w,
                                        tableV, fcwT, zb, bar);

  const _Float16* tableVc = tableV;
  _Float16* hseqa = hseq;
  unsigned* bara = bar;
  void* args[] = {(void*)&x,     (void*)&tableVc, (void*)&w_hh0,
                  (void*)&w_ih1, (void*)&w_hh1,   (void*)&b_ih1,
                  (void*)&b_hh1, (void*)&hseqa,   (void*)&bara};
  hipLaunchCooperativeKernel(lstm_mfma, dim3(256), dim3(768), args, 0, stream);

  fc_kernel<<<2048, 256, 0, stream>>>(hseq, fcwT, fc_b, out);
}

// Round 8
// 4244.379 us; speedup vs baseline: 2.4864x; 1.1494x over previous
//
#include <hip/hip_runtime.h>

// Shapes: VOCAB=128, EMBED=512, HIDDEN=1024, B=64, T=512. Inputs fp32, x int32.
// ws layout (bytes):
//   tableV : [128 vocab][4096 C] fp16   @ 0         (1 MB)  xin0+bias
//   fcwT   : [1024 k][128 v] fp16       @ 1048576   (256 KB)
//   bar    : [512 words] u32            @ 1310720   (2 KB)  flat barrier
//   hseq   : [514 buf][64 b][2048 k]f16 @ 1376256   (128.5 MB) fresh h per step
//
// Structure = R4 (best: 4360 us), ONE structural change this round:
//
// A-LOAD DEDUP / LAYER-FUSED WAVES (R8): in R4, waves 0-3 (layer0, hcat
// k<1024 = h1) and waves 4-7 (layer1 xin1 part, SAME k<1024) loaded the
// same 64 KB of A per block per step = 1/3 of all A-traffic duplicated
// in-block. Now 8 waves/block (512 thr): wave w loads k-chunk w*256 ONCE;
// waves 0-3 keep TWO B-sets (w_hh0 + w_ih1) and emit layer0 C-tiles
// (zs slots 0-3) AND layer1 C-tiles (slots 4-7); waves 4-7 keep w_hh1
// (slots 8-11). Owner reduction loops unchanged (L0: slots 0-3, L1:
// slots 4-11). Per-block A-traffic 192->128 KB/step; per-XCD L2 traffic
// 6.1->4 MB/step; fewer waves = less barrier skew. VGPR ~240 for waves
// 0-3 -> __launch_bounds__(512,2) (2 waves/SIMD, cap 256).
//
// FRESH-BUFFER h EXCHANGE (R1): step it reads buffer it, writes buffer
// it+1; consumer XCD never touched buffer it+1 before step it+1 -> plain
// cached dwordx4 loads are coherent. Stores agent-scope relaxed atomics +
// vmcnt(0) before arrival. Line-ownership: cg = (blk&7)*16+t.
// buffer[t+2][b][1024+u] IS h2[t] -> FC reads hseq directly.
// FLAT m-SPLIT BARRIER (R2): two independent single-stage barriers, arrival
// adds spread over 8 words, tid0 polls min-of-8. (R5 lesson: never increase
// same-address atomic fan-in or poller count.)
// SWIZZLED LDS REDUCTION (R4): zs[slot12][r4][rq8][col32], col32 =
// (cb*16+colp)^((rq&1)<<4), colp=j*4+g; 2-way max write conflicts, b128
// owner reads (conflicts 2.0e8 -> 2.5e7 measured). __expf + division only.
//
// Block (256 = 2 m x 128 cg): M-half m (rows m*32..+32), col-group cg
// (units cg*8..+8 of BOTH layers). Wave w (8/block): k-chunk = w*256 of
// hcat; w<4 computes L0+L1(xin1), w>=4 computes L1(hh1). Owners: waves
// 0-3 layer0 cells, 4-7 layer1 cells.

typedef _Float16 v8h __attribute__((ext_vector_type(8)));
typedef float v4f __attribute__((ext_vector_type(4)));
typedef _Float16 h2v __attribute__((ext_vector_type(2)));
typedef unsigned long long u64t;

__device__ __forceinline__ float sigf(float x) {
  return 1.0f / (1.0f + __expf(-x));
}
__device__ __forceinline__ float tanhfast(float x) {
  // tanh = 1 - 2/(e^{2x}+1); graceful at +-inf (__expf -> inf/0)
  return 1.0f - 2.0f / (1.0f + __expf(2.0f * x));
}

// ---------------------------------------------------------------- prep ----
__global__ __launch_bounds__(256) void prep_kernel(
    const float* __restrict__ emb, const float* __restrict__ w_ih0,
    const float* __restrict__ b_ih0, const float* __restrict__ b_hh0,
    const float* __restrict__ fc_w, _Float16* __restrict__ tableV,
    _Float16* __restrict__ fcwT, unsigned* __restrict__ zbuf,
    unsigned* __restrict__ bar) {
  const int blk = blockIdx.x, tid = threadIdx.x;
  if (blk < 2048) {
    // tableV[v][C] = emb[v]·w_ih0[row(C)] + b_ih0[row] + b_hh0[row]
    const int C = blk * 2 + (tid >> 7);
    const int v = tid & 127;
    const int row =
        ((C >> 2) & 3) * 1024 + (C >> 5) * 8 + ((C >> 4) & 1) * 4 + (C & 3);
    float acc = b_ih0[row] + b_hh0[row];
    const float* er = emb + v * 512;
    const float* wr = w_ih0 + row * 512;
#pragma unroll 4
    for (int k = 0; k < 512; ++k) acc = fmaf(er[k], wr[k], acc);
    tableV[v * 4096 + C] = (_Float16)acc;
  } else if (blk < 2560) {
    const int idx = (blk - 2048) * 256 + tid;   // [0, 131072)
    const int v = idx & 127, k = idx >> 7;
    fcwT[k * 128 + v] = (_Float16)fc_w[v * 1024 + k];
  } else if (blk < 2592) {
    // zero hseq buffers 0 and 1 (step-0/1 initial h state): 131072 dwords
    const int idx = (blk - 2560) * 256 + tid;
#pragma unroll
    for (int q = 0; q < 16; ++q) zbuf[idx * 16 + q] = 0u;
  } else {
    for (int i = tid; i < 512; i += 256) bar[i] = 0u;
  }
}

// ------------------------------------------------------------ recurrent ----
__global__ __launch_bounds__(512, 2) void lstm_mfma(
    const int* __restrict__ x, const _Float16* __restrict__ tableV,
    const float* __restrict__ w_hh0, const float* __restrict__ w_ih1,
    const float* __restrict__ w_hh1, const float* __restrict__ b_ih1,
    const float* __restrict__ b_hh1, _Float16* __restrict__ hseq,
    unsigned* __restrict__ bar) {
  // [slot12][r4][rq8][col32] floats, col32 = (cb*16+colp)^((rq&1)<<4): 48 KB
  __shared__ __align__(16) float zs[12 * 4 * 8 * 32];

  const int tid = threadIdx.x, blk = blockIdx.x;
  const int w = tid >> 6, l = tid & 63;
  const int lane16 = l & 15, quad = l >> 4;
  // XCD-local cg grouping: all 8 writer-blocks of any 128-B h line share
  // blk&7 (== XCD under the %8 round-robin dispatch).
  const int xcd = blk & 7, bidx = blk >> 3;
  const int m = bidx >> 4, cg = xcd * 16 + (bidx & 15);

  // --- stage B-fragments into REGISTERS (once) ---
  // breg_h: w<4 -> w_hh0 (layer0); w>=4 -> w_hh1 (layer1 high-K).
  // breg_i: w<4 only -> w_ih1 (layer1 low-K = xin1 contribution).
  v8h bh0[8], bh1[8], bi0[8], bi1[8];
  {
    const int g = lane16 >> 2, j = lane16 & 3;
    const float* Wsrc = (w < 4) ? w_hh0 : w_hh1;
    const int kbase = (w < 4) ? w * 256 : w * 256 - 1024;
#pragma unroll
    for (int cb = 0; cb < 2; ++cb) {
      const int row = g * 1024 + cg * 8 + cb * 4 + j;
      const float* rp = Wsrc + row * 1024 + kbase + quad * 8;
#pragma unroll
      for (int kk = 0; kk < 8; ++kk) {
        const float4 f0 = *(const float4*)(rp + kk * 32);
        const float4 f1 = *(const float4*)(rp + kk * 32 + 4);
        v8h b;
        b[0] = (_Float16)f0.x; b[1] = (_Float16)f0.y;
        b[2] = (_Float16)f0.z; b[3] = (_Float16)f0.w;
        b[4] = (_Float16)f1.x; b[5] = (_Float16)f1.y;
        b[6] = (_Float16)f1.z; b[7] = (_Float16)f1.w;
        if (cb == 0) bh0[kk] = b; else bh1[kk] = b;
      }
    }
    if (w < 4) {
#pragma unroll
      for (int cb = 0; cb < 2; ++cb) {
        const int row = g * 1024 + cg * 8 + cb * 4 + j;
        const float* rp = w_ih1 + row * 1024 + w * 256 + quad * 8;
#pragma unroll
        for (int kk = 0; kk < 8; ++kk) {
          const float4 f0 = *(const float4*)(rp + kk * 32);
          const float4 f1 = *(const float4*)(rp + kk * 32 + 4);
          v8h b;
          b[0] = (_Float16)f0.x; b[1] = (_Float16)f0.y;
          b[2] = (_Float16)f0.z; b[3] = (_Float16)f0.w;
          b[4] = (_Float16)f1.x; b[5] = (_Float16)f1.y;
          b[6] = (_Float16)f1.z; b[7] = (_Float16)f1.w;
          if (cb == 0) bi0[kk] = b; else bi1[kk] = b;
        }
      }
    }
  }

  // --- elementwise-owner constants ---
  const int oj = l & 7, ojj = l & 3, ocb = (l >> 2) & 1;
  const int ob = (w & 3) * 8 + (l >> 3);
  const int obg = m * 32 + ob;
  // swizzle constants
  const int colp = (lane16 & 3) * 4 + (lane16 >> 2);      // j*4+g
  const int cswz = colp ^ ((quad & 1) << 4);              // write col, cb=0
  const int rr = ob & 3, rqo = ob >> 2;                   // owner row split
  const int rcol = (ocb * 16 + ojj * 4) ^ ((rqo & 1) << 4);  // owner read col

  v4f bias4 = {0.f, 0.f, 0.f, 0.f};
  if (w >= 4) {
#pragma unroll
    for (int g = 0; g < 4; ++g) {
      const int row = g * 1024 + cg * 8 + ocb * 4 + ojj;
      bias4[g] = b_ih1[row] + b_hh1[row];
    }
  }
  _Float16 tvh[4] = {0, 0, 0, 0};
  if (w < 4) {
    const int xv = x[obg * 512];
#pragma unroll
    for (int g = 0; g < 4; ++g)
      tvh[g] = tableV[xv * 4096 + cg * 32 + ocb * 16 + g * 4 + ojj];
  }

  float cst = 0.0f;
  const int gq = blk & 7;   // arrival word within this m-half

  for (int it = 0; it <= 512; ++it) {
    const _Float16* hr = hseq + (size_t)it * 131072;       // fresh buffers
    _Float16* hw = hseq + (size_t)(it + 1) * 131072;

    // p* = layer0 tiles (w<4) or layer1-hh tiles (w>=4); q* = layer1-xin1
    v4f p00 = {0, 0, 0, 0}, p01 = {0, 0, 0, 0};
    v4f p10 = {0, 0, 0, 0}, p11 = {0, 0, 0, 0};
    v4f q00 = {0, 0, 0, 0}, q01 = {0, 0, 0, 0};
    v4f q10 = {0, 0, 0, 0}, q11 = {0, 0, 0, 0};
    const bool ld = (w < 4) || (it >= 1);
    if (ld) {
      // A: rows m*32 + mt*16 + lane16, halfs w*256 + kk*32 + quad*8
      // PLAIN CACHED loads: buffer `it` is fresh for this XCD's L2 (or
      // holds only same-XCD write-through lines) -> always coherent.
      const _Float16* a0p = hr + (m * 32 + lane16) * 2048 + w * 256 + quad * 8;
      const _Float16* a1p = a0p + 16 * 2048;
      v8h A0[8], A1[8];
#pragma unroll
      for (int kk = 0; kk < 8; ++kk) A0[kk] = *(const v8h*)(a0p + kk * 32);
#pragma unroll
      for (int kk = 0; kk < 8; ++kk) A1[kk] = *(const v8h*)(a1p + kk * 32);
      __builtin_amdgcn_sched_barrier(0);
      if (w < 4) {
        if (it < 512) {
#pragma unroll
          for (int kk = 0; kk < 8; ++kk) {
            p00 = __builtin_amdgcn_mfma_f32_16x16x32_f16(A0[kk], bh0[kk], p00, 0, 0, 0);
            p10 = __builtin_amdgcn_mfma_f32_16x16x32_f16(A0[kk], bh1[kk], p10, 0, 0, 0);
            p01 = __builtin_amdgcn_mfma_f32_16x16x32_f16(A1[kk], bh0[kk], p01, 0, 0, 0);
            p11 = __builtin_amdgcn_mfma_f32_16x16x32_f16(A1[kk], bh1[kk], p11, 0, 0, 0);
          }
        }
        if (it >= 1) {
#pragma unroll
          for (int kk = 0; kk < 8; ++kk) {
            q00 = __builtin_amdgcn_mfma_f32_16x16x32_f16(A0[kk], bi0[kk], q00, 0, 0, 0);
            q10 = __builtin_amdgcn_mfma_f32_16x16x32_f16(A0[kk], bi1[kk], q10, 0, 0, 0);
            q01 = __builtin_amdgcn_mfma_f32_16x16x32_f16(A1[kk], bi0[kk], q01, 0, 0, 0);
            q11 = __builtin_amdgcn_mfma_f32_16x16x32_f16(A1[kk], bi1[kk], q11, 0, 0, 0);
          }
        }
      } else {
#pragma unroll
        for (int kk = 0; kk < 8; ++kk) {
          p00 = __builtin_amdgcn_mfma_f32_16x16x32_f16(A0[kk], bh0[kk], p00, 0, 0, 0);
          p10 = __builtin_amdgcn_mfma_f32_16x16x32_f16(A0[kk], bh1[kk], p10, 0, 0, 0);
          p01 = __builtin_amdgcn_mfma_f32_16x16x32_f16(A1[kk], bh0[kk], p01, 0, 0, 0);
          p11 = __builtin_amdgcn_mfma_f32_16x16x32_f16(A1[kk], bh1[kk], p11, 0, 0, 0);
        }
      }
    }

    // C-tiles -> LDS, swizzled (R4 layout). Slots: w<4 -> p@w, q@w+4;
    // w>=4 -> p@w+4. Banks: 2-way max on writes.
    if (w < 4) {
#pragma unroll
      for (int r = 0; r < 4; ++r) {
        float* zpa = &zs[((w * 4 + r) * 8 + quad) * 32];
        zpa[cswz] = p00[r];
        zpa[128 + cswz] = p01[r];
        zpa[cswz ^ 16] = p10[r];
        zpa[128 + (cswz ^ 16)] = p11[r];
        float* zpb = &zs[(((w + 4) * 4 + r) * 8 + quad) * 32];
        zpb[cswz] = q00[r];
        zpb[128 + cswz] = q01[r];
        zpb[cswz ^ 16] = q10[r];
        zpb[128 + (cswz ^ 16)] = q11[r];
      }
    } else {
#pragma unroll
      for (int r = 0; r < 4; ++r) {
        float* zpb = &zs[(((w + 4) * 4 + r) * 8 + quad) * 32];
        zpb[cswz] = p00[r];
        zpb[128 + cswz] = p01[r];
        zpb[cswz ^ 16] = p10[r];
        zpb[128 + (cswz ^ 16)] = p11[r];
      }
    }
    __syncthreads();

    // owner reduction + cell update (vector b128 reads, gates contiguous)
    const bool do0 = (w < 4) && (it < 512);
    const bool do1 = (w >= 4) && (it >= 1);
    if (do0 || do1) {
      v4f z;
      if (do0) {
        z[0] = (float)tvh[0]; z[1] = (float)tvh[1];
        z[2] = (float)tvh[2]; z[3] = (float)tvh[3];
#pragma unroll
        for (int wv = 0; wv < 4; ++wv)
          z += *(const v4f*)&zs[((wv * 4 + rr) * 8 + rqo) * 32 + rcol];
      } else {
        z = bias4;
#pragma unroll
        for (int wv = 4; wv < 12; ++wv)
          z += *(const v4f*)&zs[((wv * 4 + rr) * 8 + rqo) * 32 + rcol];
      }
      const float ig = sigf(z[0]), fg = sigf(z[1]);
      const float gg = tanhfast(z[2]), og = sigf(z[3]);
      cst = fg * cst + ig * gg;
      const float hv = og * tanhfast(cst);

      // pack 8 unit-lanes (same b) -> two 8-B stores (lanes oj==0, oj==4)
      const unsigned hu =
          (unsigned)__builtin_bit_cast(unsigned short, (_Float16)hv);
      const unsigned p1 = (unsigned)__shfl_xor((int)hu, 1, 64);
      const unsigned lo = (oj & 1) ? ((p1 & 0xffffu) | (hu << 16))
                                   : ((hu & 0xffffu) | (p1 << 16));
      const unsigned p2 = (unsigned)__shfl_xor((int)lo, 2, 64);
      if ((oj & 3) == 0) {
        const u64t val = (u64t)lo | ((u64t)p2 << 32);
        if (do0) {
          __hip_atomic_store((u64t*)(hw + obg * 2048 + cg * 8 + oj), val,
                             __ATOMIC_RELAXED, __HIP_MEMORY_SCOPE_AGENT);
        } else {
          __hip_atomic_store((u64t*)(hw + obg * 2048 + 1024 + cg * 8 + oj),
                             val, __ATOMIC_RELAXED, __HIP_MEMORY_SCOPE_AGENT);
        }
      }
    }

    // prefetch next step's xin0 gather (tableV constant, L1-hot)
    if (w < 4 && it + 1 < 512) {
      const int xv = x[obg * 512 + it + 1];
#pragma unroll
      for (int g = 0; g < 4; ++g)
        tvh[g] = tableV[xv * 4096 + cg * 32 + ocb * 16 + g * 4 + ojj];
    }

    if (it < 512) {
      // ---- flat m-split barrier: one add, one poll stage, no leaders ----
      asm volatile("s_waitcnt vmcnt(0)" ::: "memory");  // h stores at L3
      __syncthreads();
      if (tid == 0) {
        atomicAdd(&bar[(m * 8 + gq) * 16], 1u);         // fire-and-forget
        const unsigned tgt = 16u * (unsigned)(it + 1);
        for (;;) {
          unsigned v[8];
#pragma unroll
          for (int g = 0; g < 8; ++g)
            v[g] = __hip_atomic_load(&bar[(m * 8 + g) * 16], __ATOMIC_RELAXED,
                                     __HIP_MEMORY_SCOPE_AGENT);
          unsigned mn = v[0];
#pragma unroll
          for (int g = 1; g < 8; ++g) mn = (v[g] < mn) ? v[g] : mn;
          if (mn >= tgt) break;
          __builtin_amdgcn_s_sleep(1);
        }
      }
      __syncthreads();
      // keep the fresh-buffer plain loads from being hoisted above release
      asm volatile("" ::: "memory");
    }
  }
}

// ---------------------------------------------------------------- FC ----
__global__ __launch_bounds__(256, 2) void fc_kernel(
    const _Float16* __restrict__ hseq, const _Float16* __restrict__ fcwT,
    const float* __restrict__ fc_b, float* __restrict__ out) {
  __shared__ float hl[16][1024];      // 64 KB
  const int tid = threadIdx.x;
  const int t = blockIdx.x >> 2, bs = blockIdx.x & 3;
  const int v = tid & 127, hh = tid >> 7;

  // h2[t][b][u] lives at hseq buffer t+2, row b, halfs 1024..2047
  const h2v* hp = (const h2v*)hseq;
  const size_t base = (size_t)(t + 2) * 65536 + 512;
  for (int idx = tid; idx < 8192; idx += 256) {
    const int bl = idx >> 9, kp = idx & 511;
    const h2v pr = hp[base + (size_t)((bs * 16 + bl)) * 1024 + kp];
    hl[bl][2 * kp] = (float)pr.x;
    hl[bl][2 * kp + 1] = (float)pr.y;
  }
  __syncthreads();

  float acc[8];
#pragma unroll
  for (int i = 0; i < 8; ++i) acc[i] = 0.0f;
  const int bl0 = hh * 8;
#pragma unroll 1
  for (int k4 = 0; k4 < 256; ++k4) {
    const int k = k4 * 4;
    const float w0 = (float)fcwT[(k + 0) * 128 + v];
    const float w1 = (float)fcwT[(k + 1) * 128 + v];
    const float w2 = (float)fcwT[(k + 2) * 128 + v];
    const float w3 = (float)fcwT[(k + 3) * 128 + v];
#pragma unroll
    for (int i = 0; i < 8; ++i) {
      const float4 hv = *(const float4*)&hl[bl0 + i][k];
      acc[i] += hv.x * w0 + hv.y * w1 + hv.z * w2 + hv.w * w3;
    }
  }
  const float bias = fc_b[v];
#pragma unroll
  for (int i = 0; i < 8; ++i) {
    const int bb = bs * 16 + bl0 + i;
    out[(bb * 512 + t) * 128 + v] = acc[i] + bias;
  }
}

// ------------------------------------------------------------- launch ----
extern "C" void kernel_launch(void* const* d_in, const int* in_sizes, int n_in,
                              void* d_out, int out_size, void* d_ws,
                              size_t ws_size, hipStream_t stream) {
  const int* x = (const int*)d_in[0];
  const float* emb = (const float*)d_in[1];
  const float* w_ih0 = (const float*)d_in[2];
  const float* w_hh0 = (const float*)d_in[3];
  const float* b_ih0 = (const float*)d_in[4];
  const float* b_hh0 = (const float*)d_in[5];
  const float* w_ih1 = (const float*)d_in[6];
  const float* w_hh1 = (const float*)d_in[7];
  const float* b_ih1 = (const float*)d_in[8];
  const float* b_hh1 = (const float*)d_in[9];
  const float* fc_w = (const float*)d_in[10];
  const float* fc_b = (const float*)d_in[11];
  float* out = (float*)d_out;

  char* ws = (char*)d_ws;
  _Float16* tableV = (_Float16*)(ws);
  _Float16* fcwT = (_Float16*)(ws + 1048576);
  unsigned* bar = (unsigned*)(ws + 1310720);
  _Float16* hseq = (_Float16*)(ws + 1376256);   // 514 x 262144 B
  unsigned* zb = (unsigned*)(ws + 1376256);     // zero buffers 0,1

  prep_kernel<<<2593, 256, 0, stream>>>(emb, w_ih0, b_ih0, b_hh0, fc_w,
                                        tableV, fcwT, zb, bar);

  const _Float16* tableVc = tableV;
  _Float16* hseqa = hseq;
  unsigned* bara = bar;
  void* args[] = {(void*)&x,     (void*)&tableVc, (void*)&w_hh0,
                  (void*)&w_ih1, (void*)&w_hh1,   (void*)&b_ih1,
                  (void*)&b_hh1, (void*)&hseqa,   (void*)&bara};
  hipLaunchCooperativeKernel(lstm_mfma, dim3(256), dim3(512), args, 0, stream);

  fc_kernel<<<2048, 256, 0, stream>>>(hseq, fcwT, fc_b, out);
}